// Round 15
// baseline (424.558 us; speedup 1.0000x reference)
//
#include <hip/hip_runtime.h>
#include <hip/hip_bf16.h>
#include <stdint.h>
#include <math.h>

// TreeLSTM on MI355X — v22: v21 + software-pipelined tail K-loops.
// v21 post-mortem: tail clean of spill (WRITE 3.7MB) but latency-sick
// (106us, MfmaUtil 6.6%): the unroll-1 spill fix removed ALL pipelining —
// every K-step waits ~300cy for its 5 global B loads. LDS-B impossible
// (16 waves need 16 different 80KB ct-slices). v22: manual unroll-2
// rotation with two NAMED static B buffers (no dynamic reg indexing, no
// address-table blowup — still 5 walking pointers): prefetch step s+1's B
// before step s's A+MFMA. Applied to lev6-chunk and lev5..1 loops.
// Everything else byte-identical to v21.

typedef __bf16 bf16x8 __attribute__((ext_vector_type(8)));
typedef float  f32x4  __attribute__((ext_vector_type(4)));
typedef int    i32x4  __attribute__((ext_vector_type(4)));

__device__ __forceinline__ float sigf(float x) { return 1.f / (1.f + __expf(-x)); }
__device__ __forceinline__ float tanhfast(float x) {
    return 1.f - 2.f / (__expf(2.f * x) + 1.f);   // stable at |x| large
}

// blocks 0..255: xg4; blocks 256..575: BtP pack.
__global__ void prep_kernel(const float* __restrict__ emb, const float* __restrict__ W,
                            const float* __restrict__ bW, const float* __restrict__ U,
                            float* __restrict__ xg4, __bf16* __restrict__ BtP) {
    if (blockIdx.x < 256) {
        int g = blockIdx.x >> 6, v = blockIdx.x & 63, k = threadIdx.x;
        __shared__ float e[256];
        e[k] = emb[v * 256 + k];
        __syncthreads();
        float s = bW[g * 256 + k];
        const float* Wg = W + g * 65536 + k;
#pragma unroll 4
        for (int i = 0; i < 256; i++) s += e[i] * Wg[i * 256];
        xg4[(v * 256 + k) * 4 + g] = s;
    } else {
        int t = (blockIdx.x - 256) * 256 + threadIdx.x;   // < 81920
        int g    = t >> 14;
        int r    = t & 16383;
        int ct   = r >> 10;
        int ks   = (r >> 6) & 15;
        int lane = t & 63;
        int lr = lane & 15, q = lane >> 4;
        int col = ct * 16 + lr;
        int kbase = ks * 32 + q * 8;
        bf16x8 v8;
#pragma unroll
        for (int e2 = 0; e2 < 8; e2++) {
            int k = kbase + e2;
            int s = k >> 8, kk = k & 255;
            v8[e2] = (__bf16)U[((g * 2 + s) * 256 + kk) * 256 + col];
        }
        *(bf16x8*)(BtP + (long)t * 8) = v8;
    }
}

__global__ void leaf_kernel(const int* __restrict__ ids, const float* __restrict__ xg4,
                            __bf16* __restrict__ h, __bf16* __restrict__ c) {
    int col = threadIdx.x;                 // 0..255
    int r0 = blockIdx.x * 32;              // 2048 blocks x 32 rows
    for (int r = r0; r < r0 + 32; r++) {
        int b = r >> 10, j = r & 1023;
        int id = ids[b * 2046 + 1022 + j];
        f32x4 xv = *(const f32x4*)(xg4 + (id * 256 + col) * 4);
        float ig = sigf(xv.y);
        float og = sigf(xv.z);
        float ug = tanhfast(xv.w);
        float cv = ig * ug;
        float hv = og * tanhfast(cv);
        h[r * 256 + col] = (__bf16)hv;
        c[r * 256 + col] = (__bf16)cv;
    }
}

// ===== big levels (9..7): v12b measured kernel, byte-exact =====
__global__ __launch_bounds__(1024, 4) void level_kernel(
    const __bf16* __restrict__ A, const __bf16* __restrict__ Cprev,
    const __bf16* __restrict__ BtP, const float* __restrict__ xg4,
    const int* __restrict__ ids, __bf16* __restrict__ h_out,
    __bf16* __restrict__ c_out, float* __restrict__ rh_out,
    int lev, int M, int RG, int NB, int NB16) {
    __shared__ __bf16 Blds[5 * 16 * 512];     // 80 KB
    const int gid = blockIdx.x;
    int rgslot, ct;
    if (NB16) { rgslot = gid & 15; ct = gid >> 4; }   // XCD-affine: gid%8==rg%8
    else      { rgslot = gid % NB; ct = gid / NB; }
    const int tid  = threadIdx.x;
    const int wave = tid >> 6;
    const int lane = tid & 63;
    const int lr = lane & 15, q = lane >> 4;
    const int gcol = ct * 16 + lr;
    const int n = 1 << lev;

#pragma unroll
    for (int i = 0; i < 5; i++) {
        int cc = tid + i * 1024;
        int g = cc >> 10;
        int r = cc & 1023;
        *(i32x4*)(&Blds[g * 8192 + r * 8]) =
            *(const i32x4*)(BtP + (long)(g * 16 + ct) * 8192 + r * 8);
    }
    __syncthreads();

    int rg0 = rgslot;
    long wrow = (long)rg0 * 512 + wave * 32;
    const __bf16* Ap = A + (wrow + lr) * 512 + q * 8;   // + mt*8192 + s*32
    bf16x8 af[4][2];
    if (wrow < M) {
#pragma unroll
        for (int mt = 0; mt < 2; mt++) {
            af[0][mt] = *(const bf16x8*)(Ap + mt * 8192);
            af[1][mt] = *(const bf16x8*)(Ap + mt * 8192 + 32);
        }
    }

    for (int rg = rg0; rg < RG; rg += NB) {
        wrow = (long)rg * 512 + wave * 32;
        const bool active = (wrow < M);

        int rgn = rg + NB;
        long wrown = (rgn < RG) ? ((long)rgn * 512 + wave * 32) : wrow;
        const __bf16* Apn = A + (wrown + lr) * 512 + q * 8;

        int idv[2][4];
        __bf16 clv[2][4], crv[2][4];
        if (active) {
#pragma unroll
            for (int mt = 0; mt < 2; mt++)
#pragma unroll
                for (int v = 0; v < 4; v++) {
                    long grow = wrow + mt * 16 + q * 4 + v;
                    int b = (int)(grow >> lev);
                    int j = (int)(grow & (n - 1));
                    idv[mt][v] = ids[b * 2046 + (n - 2) + j];
                    clv[mt][v] = Cprev[grow * 512 + gcol];
                    crv[mt][v] = Cprev[grow * 512 + 256 + gcol];
                }
        }

        if (active) {
            f32x4 acc[5][2];
#pragma unroll
            for (int g2 = 0; g2 < 5; g2++)
#pragma unroll
                for (int mt = 0; mt < 2; mt++)
                    acc[g2][mt] = (f32x4){0.f, 0.f, 0.f, 0.f};

            bf16x8 bb[2][5];
#pragma unroll
            for (int g2 = 0; g2 < 5; g2++)
                bb[0][g2] = *(const bf16x8*)(&Blds[g2 * 8192 + lane * 8]);

#pragma unroll
            for (int s = 0; s < 16; s++) {
                {   // A: 2 ahead; wraps into NEXT rg's steps 0,1 at s=14,15.
                    int sp = s + 2;
                    const __bf16* P = (sp < 16) ? Ap : Apn;
                    int so = sp & 15;
#pragma unroll
                    for (int mt = 0; mt < 2; mt++)
                        af[sp & 3][mt] = *(const bf16x8*)(P + mt * 8192 + so * 32);
                }
                if (s + 1 < 16) {                  // B: 1 step ahead from LDS
#pragma unroll
                    for (int g2 = 0; g2 < 5; g2++)
                        bb[(s + 1) & 1][g2] =
                            *(const bf16x8*)(&Blds[g2 * 8192 + (s + 1) * 512 + lane * 8]);
                }
#pragma unroll
                for (int g2 = 0; g2 < 5; g2++)
#pragma unroll
                    for (int mt = 0; mt < 2; mt++)
                        acc[g2][mt] = __builtin_amdgcn_mfma_f32_16x16x32_bf16(
                            af[s & 3][mt], bb[s & 1][g2], acc[g2][mt], 0, 0, 0);
            }

#pragma unroll
            for (int mt = 0; mt < 2; mt++) {
#pragma unroll
                for (int v = 0; v < 4; v++) {
                    long grow = wrow + mt * 16 + q * 4 + v;
                    f32x4 xv = *(const f32x4*)(xg4 + (idv[mt][v] * 256 + gcol) * 4);
                    float fl = sigf(acc[0][mt][v] + xv.x);   // f_l,f_r share gate0
                    float fr = sigf(acc[1][mt][v] + xv.x);
                    float ig = sigf(acc[2][mt][v] + xv.y);
                    float og = sigf(acc[3][mt][v] + xv.z);
                    float ug = tanhfast(acc[4][mt][v] + xv.w);
                    float cv = ig * ug + fl * (float)clv[mt][v]
                                       + fr * (float)crv[mt][v];
                    float hv = og * tanhfast(cv);
                    h_out[grow * 256 + gcol] = (__bf16)hv;
                    c_out[grow * 256 + gcol] = (__bf16)cv;
                    if (rh_out) rh_out[grow * 256 + gcol] = hv;
                }
            }
        }
        Ap = Apn;
    }
}

#define LOADB5(dst)                                                            \
    do {                                                                       \
        dst[0] = *(const bf16x8*)bp0; dst[1] = *(const bf16x8*)bp1;            \
        dst[2] = *(const bf16x8*)bp2; dst[3] = *(const bf16x8*)bp3;            \
        dst[4] = *(const bf16x8*)bp4;                                          \
        bp0 += 512; bp1 += 512; bp2 += 512; bp3 += 512; bp4 += 512;            \
    } while (0)

// ===== tail: lev6..1 + scores. 64 blocks (one per batch), 1024 thr = 16
// waves (wave = ct). Stage lev7 output (128 rows h+c, swizzled) into LDS.
// lev6 IN-PLACE (2 chunks, read/write phases); lev5..1 ping-pong. K-loops
// software-pipelined: unroll-2 with two named B buffers (prefetch s+1's B
// before s's A+MFMA) — static indices, 5 walking pointers, no spill.
__global__ __launch_bounds__(1024, 4) void tail_kernel(
    const __bf16* __restrict__ Hin, const __bf16* __restrict__ Cin,
    const __bf16* __restrict__ BtP, const float* __restrict__ xg4,
    const int* __restrict__ ids, const float* __restrict__ Ws,
    const float* __restrict__ bs, float* __restrict__ out) {
    __shared__ __bf16 hbuf[128 * 256];   // 64 KB
    __shared__ __bf16 cbuf[128 * 256];   // 64 KB
    const int b    = blockIdx.x;
    const int tid  = threadIdx.x;
    const int wave = tid >> 6;           // = ct
    const int lane = tid & 63;
    const int lr = lane & 15, q = lane >> 4;
    const int ct   = wave;
    const int gcol = ct * 16 + lr;

    // ---- Stage lev-7 output (batch b: 128 rows) into rows [0,128), swizzled. --
#pragma unroll
    for (int i = 0; i < 4; i++) {
        int idx = tid + i * 1024;            // 16B granule, 0..4095
        int row = idx >> 5;                  // 0..127
        int colb = (idx & 31) * 16;
        int dst = (row * 512 + colb) ^ (((row >> 1) & 7) << 4);
        *(i32x4*)((char*)hbuf + dst) =
            *(const i32x4*)(Hin + (long)(b * 128 + row) * 256 + (idx & 31) * 8);
        *(i32x4*)((char*)cbuf + dst) =
            *(const i32x4*)(Cin + (long)(b * 128 + row) * 256 + (idx & 31) * 8);
    }
    __syncthreads();

    const __bf16* Bbase = BtP + (long)ct * 8192 + lane * 8;  // + g2*131072 + s*512

    // ---- lev6 IN-PLACE: n=64, 2 chunks of 32 parents. ----
#pragma unroll 1
    for (int ch = 0; ch < 2; ch++) {
        const int rbase = ch * 32;

        // READ PHASE: ids + child c + K-loop + gates -> regs.
        int idv6[2][4];
        float clv6[2][4], crv6[2][4];
#pragma unroll
        for (int mt = 0; mt < 2; mt++)
#pragma unroll
            for (int v = 0; v < 4; v++) {
                int j = rbase + mt * 16 + q * 4 + v;          // < 64
                idv6[mt][v] = ids[b * 2046 + 62 + j];
                int c0r = 2 * j, c1r = 2 * j + 1;
                int a0 = (c0r * 512 + gcol * 2) ^ (((c0r >> 1) & 7) << 4);
                int a1 = (c1r * 512 + gcol * 2) ^ (((c1r >> 1) & 7) << 4);
                clv6[mt][v] = (float)*(const __bf16*)((const char*)cbuf + a0);
                crv6[mt][v] = (float)*(const __bf16*)((const char*)cbuf + a1);
            }

        f32x4 acc[5][2];
#pragma unroll
        for (int g2 = 0; g2 < 5; g2++)
#pragma unroll
            for (int mt = 0; mt < 2; mt++)
                acc[g2][mt] = (f32x4){0.f, 0.f, 0.f, 0.f};

        const __bf16* bp0 = Bbase;
        const __bf16* bp1 = Bbase + 131072;
        const __bf16* bp2 = Bbase + 262144;
        const __bf16* bp3 = Bbase + 393216;
        const __bf16* bp4 = Bbase + 524288;

        bf16x8 b0_[5], b1_[5];
        LOADB5(b0_);                          // s = 0

#pragma unroll 1
        for (int s2 = 0; s2 < 8; s2++) {
            const int s = s2 * 2;
            LOADB5(b1_);                      // prefetch s+1

            bf16x8 afv[2];
            {
                int k0 = q * 8 + s * 32;
                int crow = 2 * (rbase + lr) + (k0 >> 8);
                int ab = (crow * 512 + (k0 & 255) * 2) ^ (((crow >> 1) & 7) << 4);
                afv[0] = *(const bf16x8*)((const char*)hbuf + ab);
                crow = 2 * (rbase + 16 + lr) + (k0 >> 8);
                ab = (crow * 512 + (k0 & 255) * 2) ^ (((crow >> 1) & 7) << 4);
                afv[1] = *(const bf16x8*)((const char*)hbuf + ab);
            }
#pragma unroll
            for (int g2 = 0; g2 < 5; g2++)
#pragma unroll
                for (int mt = 0; mt < 2; mt++)
                    acc[g2][mt] = __builtin_amdgcn_mfma_f32_16x16x32_bf16(
                        afv[mt], b0_[g2], acc[g2][mt], 0, 0, 0);

            if (s2 < 7) LOADB5(b0_);          // prefetch s+2

            {
                int k0 = q * 8 + (s + 1) * 32;
                int crow = 2 * (rbase + lr) + (k0 >> 8);
                int ab = (crow * 512 + (k0 & 255) * 2) ^ (((crow >> 1) & 7) << 4);
                afv[0] = *(const bf16x8*)((const char*)hbuf + ab);
                crow = 2 * (rbase + 16 + lr) + (k0 >> 8);
                ab = (crow * 512 + (k0 & 255) * 2) ^ (((crow >> 1) & 7) << 4);
                afv[1] = *(const bf16x8*)((const char*)hbuf + ab);
            }
#pragma unroll
            for (int g2 = 0; g2 < 5; g2++)
#pragma unroll
                for (int mt = 0; mt < 2; mt++)
                    acc[g2][mt] = __builtin_amdgcn_mfma_f32_16x16x32_bf16(
                        afv[mt], b1_[g2], acc[g2][mt], 0, 0, 0);
        }

        float hv6[2][4], cv6[2][4];
#pragma unroll
        for (int mt = 0; mt < 2; mt++)
#pragma unroll
            for (int v = 0; v < 4; v++) {
                f32x4 xv = *(const f32x4*)(xg4 + (idv6[mt][v] * 256 + gcol) * 4);
                float fl = sigf(acc[0][mt][v] + xv.x);
                float fr = sigf(acc[1][mt][v] + xv.x);
                float ig = sigf(acc[2][mt][v] + xv.y);
                float og = sigf(acc[3][mt][v] + xv.z);
                float ug = tanhfast(acc[4][mt][v] + xv.w);
                float cv = ig * ug + fl * clv6[mt][v] + fr * crv6[mt][v];
                cv6[mt][v] = cv;
                hv6[mt][v] = og * tanhfast(cv);
            }
        __syncthreads();    // all reads of this chunk complete

        // WRITE PHASE: rows rbase..rbase+31 (disjoint from other chunk's reads).
#pragma unroll
        for (int mt = 0; mt < 2; mt++)
#pragma unroll
            for (int v = 0; v < 4; v++) {
                int j = rbase + mt * 16 + q * 4 + v;
                int dst = (j * 512 + gcol * 2) ^ (((j >> 1) & 7) << 4);
                *(__bf16*)((char*)hbuf + dst) = (__bf16)hv6[mt][v];
                *(__bf16*)((char*)cbuf + dst) = (__bf16)cv6[mt][v];
            }
        __syncthreads();
    }

    // ---- lev5..1: ping-pong [0,64) <-> [64,96). ----
#pragma unroll 1
    for (int lev = 5; lev >= 1; lev--) {
        const int n   = 1 << lev;
        const int off = n - 2;
        const int p   = (5 - lev) & 1;
        const int rr  = p ? 64 : 0;          // read region start row
        const int wr  = p ? 0 : 64;          // write region start row
        const int mts = (n > 16) ? 2 : 1;

        int idv[2][4];
#pragma unroll
        for (int mt = 0; mt < 2; mt++)
#pragma unroll
            for (int v = 0; v < 4; v++) {
                int j = mt * 16 + q * 4 + v;
                idv[mt][v] = ids[b * 2046 + off + ((j < n) ? j : 0)];
            }

        f32x4 acc[5][2];
#pragma unroll
        for (int g2 = 0; g2 < 5; g2++)
#pragma unroll
            for (int mt = 0; mt < 2; mt++)
                acc[g2][mt] = (f32x4){0.f, 0.f, 0.f, 0.f};

        const __bf16* bp0 = Bbase;
        const __bf16* bp1 = Bbase + 131072;
        const __bf16* bp2 = Bbase + 262144;
        const __bf16* bp3 = Bbase + 393216;
        const __bf16* bp4 = Bbase + 524288;

        bf16x8 b0_[5], b1_[5];
        LOADB5(b0_);                          // s = 0

#pragma unroll 1
        for (int s2 = 0; s2 < 8; s2++) {
            const int s = s2 * 2;
            LOADB5(b1_);                      // prefetch s+1

            bf16x8 afv[2];
            {
                int k0 = q * 8 + s * 32;
                int crow = rr + 2 * lr + (k0 >> 8);
                int ab = (crow * 512 + (k0 & 255) * 2) ^ (((crow >> 1) & 7) << 4);
                afv[0] = *(const bf16x8*)((const char*)hbuf + ab);
                if (mts > 1) {
                    crow = rr + 2 * (16 + lr) + (k0 >> 8);
                    ab = (crow * 512 + (k0 & 255) * 2) ^ (((crow >> 1) & 7) << 4);
                    afv[1] = *(const bf16x8*)((const char*)hbuf + ab);
                } else afv[1] = afv[0];
            }
#pragma unroll
            for (int g2 = 0; g2 < 5; g2++)
#pragma unroll
                for (int mt = 0; mt < 2; mt++)
                    acc[g2][mt] = __builtin_amdgcn_mfma_f32_16x16x32_bf16(
                        afv[mt], b0_[g2], acc[g2][mt], 0, 0, 0);

            if (s2 < 7) LOADB5(b0_);          // prefetch s+2

            {
                int k0 = q * 8 + (s + 1) * 32;
                int crow = rr + 2 * lr + (k0 >> 8);
                int ab = (crow * 512 + (k0 & 255) * 2) ^ (((crow >> 1) & 7) << 4);
                afv[0] = *(const bf16x8*)((const char*)hbuf + ab);
                if (mts > 1) {
                    crow = rr + 2 * (16 + lr) + (k0 >> 8);
                    ab = (crow * 512 + (k0 & 255) * 2) ^ (((crow >> 1) & 7) << 4);
                    afv[1] = *(const bf16x8*)((const char*)hbuf + ab);
                } else afv[1] = afv[0];
            }
#pragma unroll
            for (int g2 = 0; g2 < 5; g2++)
#pragma unroll
                for (int mt = 0; mt < 2; mt++)
                    acc[g2][mt] = __builtin_amdgcn_mfma_f32_16x16x32_bf16(
                        afv[mt], b1_[g2], acc[g2][mt], 0, 0, 0);
        }

#pragma unroll
        for (int mt = 0; mt < 2; mt++) {
#pragma unroll
            for (int v = 0; v < 4; v++) {
                int j = mt * 16 + q * 4 + v;
                if (mt < mts && j < n) {
                    int c0r = rr + 2 * j, c1r = rr + 2 * j + 1;
                    int a0 = (c0r * 512 + gcol * 2) ^ (((c0r >> 1) & 7) << 4);
                    int a1 = (c1r * 512 + gcol * 2) ^ (((c1r >> 1) & 7) << 4);
                    float cl = (float)*(const __bf16*)((const char*)cbuf + a0);
                    float cr = (float)*(const __bf16*)((const char*)cbuf + a1);
                    f32x4 xv = *(const f32x4*)(xg4 + (idv[mt][v] * 256 + gcol) * 4);
                    float fl = sigf(acc[0][mt][v] + xv.x);
                    float fr = sigf(acc[1][mt][v] + xv.x);
                    float ig = sigf(acc[2][mt][v] + xv.y);
                    float og = sigf(acc[3][mt][v] + xv.z);
                    float ug = tanhfast(acc[4][mt][v] + xv.w);
                    float cv = ig * ug + fl * cl + fr * cr;
                    float hv = og * tanhfast(cv);
                    int drow = wr + j;
                    int dst = (drow * 512 + gcol * 2) ^ (((drow >> 1) & 7) << 4);
                    *(__bf16*)((char*)hbuf + dst) = (__bf16)hv;
                    if (lev > 1) *(__bf16*)((char*)cbuf + dst) = (__bf16)cv;
                    if (lev == 1) out[192 + b * 512 + j * 256 + gcol] = hv;
                }
            }
        }
        __syncthreads();
    }

    // ---- scores: lev1 h sits in rows 64,65 (swizzle identity there). ----
    if (tid < 192) {
        int t = tid >> 6, ln = tid & 63;
        float s = 0.f;
        for (int i = ln; i < 512; i += 64) {
            int row = 64 + (i >> 8);
            float hv = (float)hbuf[row * 256 + (i & 255)];
            s += hv * Ws[i * 3 + t];
        }
        for (int o = 32; o > 0; o >>= 1) s += __shfl_down(s, o);
        if (ln == 0) out[b * 3 + t] = s + bs[t];
    }
}

extern "C" void kernel_launch(void* const* d_in, const int* in_sizes, int n_in,
                              void* d_out, int out_size, void* d_ws, size_t ws_size,
                              hipStream_t stream) {
    const int*   ids = (const int*)  d_in[0];
    const float* emb = (const float*)d_in[1];
    const float* W   = (const float*)d_in[2];
    const float* bW  = (const float*)d_in[3];
    const float* U   = (const float*)d_in[4];
    const float* Ws  = (const float*)d_in[5];
    const float* bs  = (const float*)d_in[6];
    float* out = (float*)d_out;   // [0:192) scores, [192:) root_hidden (64x512)

    char* ws = (char*)d_ws;
    float*  xg4 = (float*)ws;                   //   262144 B : xg4[64][256][4]
    __bf16* BtP = (__bf16*)(ws + 262144);       //  1310720 B : packed B fragments
    __bf16* h0  = (__bf16*)(ws + 1572864);      // 33554432 B : h ping (leaf-sized)
    __bf16* c0  = (__bf16*)(ws + 35127296);     // 33554432 B
    __bf16* h1  = (__bf16*)(ws + 68681728);     // 16777216 B : h pong
    __bf16* c1  = (__bf16*)(ws + 85458944);     // 16777216 B   (total 102236160 B)

    prep_kernel<<<dim3(576), dim3(256), 0, stream>>>(emb, W, bW, U, xg4, BtP);
    leaf_kernel<<<dim3(2048), dim3(256), 0, stream>>>(ids, xg4, h0, c0);

    __bf16* hb[2] = {h0, h1};
    __bf16* cb[2] = {c0, c1};
    int cur = 0;
    for (int lev = 9; lev >= 7; lev--) {
        int M = 64 << lev;                      // B * 2^lev rows
        int RG = M >> 9;
        int NB = (RG < 16) ? RG : 16;
        level_kernel<<<dim3(16 * NB), dim3(1024), 0, stream>>>(
            hb[cur], cb[cur], BtP, xg4, ids, hb[1 - cur], cb[1 - cur], nullptr,
            lev, M, RG, NB, (NB == 16) ? 1 : 0);
        cur = 1 - cur;
    }
    // after lev7: cur==1 -> h1/c1 hold lev-7 output (8192 rows = 64 x 128)
    tail_kernel<<<dim3(64), dim3(1024), 0, stream>>>(
        hb[cur], cb[cur], BtP, xg4, ids, Ws, bs, out);
}

// Round 16
// 377.083 us; speedup vs baseline: 1.1259x; 1.1259x over previous
//
#include <hip/hip_runtime.h>
#include <hip/hip_bf16.h>
#include <stdint.h>
#include <math.h>

// TreeLSTM on MI355X — v23: tail with BOTH spill constraints satisfied.
// v22 post-mortem: dbuf pipelining needs ~150 regs; a 1024-thr block (16
// waves = 4 waves/SIMD) caps at 128 -> re-spill (WRITE 32MB). v23 tail:
// 512 thr = 8 waves -> 2 waves/SIMD -> 256-reg budget; each wave runs two
// cts sequentially (ct = wave + 8*cp, unroll-1 cp loop -> one cp live).
// Keeps the v20/v21 spill-law fixes: rolled K-loop, 5 walking B pointers,
// two NAMED static B buffers, static reg indices. lev6 stays folded
// (in-place 2-chunk read/write phasing, correctness-verified in v21/v22).
// prep/leaf/lev9..7 byte-exact v20.

typedef __bf16 bf16x8 __attribute__((ext_vector_type(8)));
typedef float  f32x4  __attribute__((ext_vector_type(4)));
typedef int    i32x4  __attribute__((ext_vector_type(4)));

__device__ __forceinline__ float sigf(float x) { return 1.f / (1.f + __expf(-x)); }
__device__ __forceinline__ float tanhfast(float x) {
    return 1.f - 2.f / (__expf(2.f * x) + 1.f);   // stable at |x| large
}

// blocks 0..255: xg4; blocks 256..575: BtP pack.
__global__ void prep_kernel(const float* __restrict__ emb, const float* __restrict__ W,
                            const float* __restrict__ bW, const float* __restrict__ U,
                            float* __restrict__ xg4, __bf16* __restrict__ BtP) {
    if (blockIdx.x < 256) {
        int g = blockIdx.x >> 6, v = blockIdx.x & 63, k = threadIdx.x;
        __shared__ float e[256];
        e[k] = emb[v * 256 + k];
        __syncthreads();
        float s = bW[g * 256 + k];
        const float* Wg = W + g * 65536 + k;
#pragma unroll 4
        for (int i = 0; i < 256; i++) s += e[i] * Wg[i * 256];
        xg4[(v * 256 + k) * 4 + g] = s;
    } else {
        int t = (blockIdx.x - 256) * 256 + threadIdx.x;   // < 81920
        int g    = t >> 14;
        int r    = t & 16383;
        int ct   = r >> 10;
        int ks   = (r >> 6) & 15;
        int lane = t & 63;
        int lr = lane & 15, q = lane >> 4;
        int col = ct * 16 + lr;
        int kbase = ks * 32 + q * 8;
        bf16x8 v8;
#pragma unroll
        for (int e2 = 0; e2 < 8; e2++) {
            int k = kbase + e2;
            int s = k >> 8, kk = k & 255;
            v8[e2] = (__bf16)U[((g * 2 + s) * 256 + kk) * 256 + col];
        }
        *(bf16x8*)(BtP + (long)t * 8) = v8;
    }
}

__global__ void leaf_kernel(const int* __restrict__ ids, const float* __restrict__ xg4,
                            __bf16* __restrict__ h, __bf16* __restrict__ c) {
    int col = threadIdx.x;                 // 0..255
    int r0 = blockIdx.x * 32;              // 2048 blocks x 32 rows
    for (int r = r0; r < r0 + 32; r++) {
        int b = r >> 10, j = r & 1023;
        int id = ids[b * 2046 + 1022 + j];
        f32x4 xv = *(const f32x4*)(xg4 + (id * 256 + col) * 4);
        float ig = sigf(xv.y);
        float og = sigf(xv.z);
        float ug = tanhfast(xv.w);
        float cv = ig * ug;
        float hv = og * tanhfast(cv);
        h[r * 256 + col] = (__bf16)hv;
        c[r * 256 + col] = (__bf16)cv;
    }
}

// ===== big levels (9..7): v12b measured kernel, byte-exact =====
__global__ __launch_bounds__(1024, 4) void level_kernel(
    const __bf16* __restrict__ A, const __bf16* __restrict__ Cprev,
    const __bf16* __restrict__ BtP, const float* __restrict__ xg4,
    const int* __restrict__ ids, __bf16* __restrict__ h_out,
    __bf16* __restrict__ c_out, float* __restrict__ rh_out,
    int lev, int M, int RG, int NB, int NB16) {
    __shared__ __bf16 Blds[5 * 16 * 512];     // 80 KB
    const int gid = blockIdx.x;
    int rgslot, ct;
    if (NB16) { rgslot = gid & 15; ct = gid >> 4; }   // XCD-affine: gid%8==rg%8
    else      { rgslot = gid % NB; ct = gid / NB; }
    const int tid  = threadIdx.x;
    const int wave = tid >> 6;
    const int lane = tid & 63;
    const int lr = lane & 15, q = lane >> 4;
    const int gcol = ct * 16 + lr;
    const int n = 1 << lev;

#pragma unroll
    for (int i = 0; i < 5; i++) {
        int cc = tid + i * 1024;
        int g = cc >> 10;
        int r = cc & 1023;
        *(i32x4*)(&Blds[g * 8192 + r * 8]) =
            *(const i32x4*)(BtP + (long)(g * 16 + ct) * 8192 + r * 8);
    }
    __syncthreads();

    int rg0 = rgslot;
    long wrow = (long)rg0 * 512 + wave * 32;
    const __bf16* Ap = A + (wrow + lr) * 512 + q * 8;   // + mt*8192 + s*32
    bf16x8 af[4][2];
    if (wrow < M) {
#pragma unroll
        for (int mt = 0; mt < 2; mt++) {
            af[0][mt] = *(const bf16x8*)(Ap + mt * 8192);
            af[1][mt] = *(const bf16x8*)(Ap + mt * 8192 + 32);
        }
    }

    for (int rg = rg0; rg < RG; rg += NB) {
        wrow = (long)rg * 512 + wave * 32;
        const bool active = (wrow < M);

        int rgn = rg + NB;
        long wrown = (rgn < RG) ? ((long)rgn * 512 + wave * 32) : wrow;
        const __bf16* Apn = A + (wrown + lr) * 512 + q * 8;

        int idv[2][4];
        __bf16 clv[2][4], crv[2][4];
        if (active) {
#pragma unroll
            for (int mt = 0; mt < 2; mt++)
#pragma unroll
                for (int v = 0; v < 4; v++) {
                    long grow = wrow + mt * 16 + q * 4 + v;
                    int b = (int)(grow >> lev);
                    int j = (int)(grow & (n - 1));
                    idv[mt][v] = ids[b * 2046 + (n - 2) + j];
                    clv[mt][v] = Cprev[grow * 512 + gcol];
                    crv[mt][v] = Cprev[grow * 512 + 256 + gcol];
                }
        }

        if (active) {
            f32x4 acc[5][2];
#pragma unroll
            for (int g2 = 0; g2 < 5; g2++)
#pragma unroll
                for (int mt = 0; mt < 2; mt++)
                    acc[g2][mt] = (f32x4){0.f, 0.f, 0.f, 0.f};

            bf16x8 bb[2][5];
#pragma unroll
            for (int g2 = 0; g2 < 5; g2++)
                bb[0][g2] = *(const bf16x8*)(&Blds[g2 * 8192 + lane * 8]);

#pragma unroll
            for (int s = 0; s < 16; s++) {
                {   // A: 2 ahead; wraps into NEXT rg's steps 0,1 at s=14,15.
                    int sp = s + 2;
                    const __bf16* P = (sp < 16) ? Ap : Apn;
                    int so = sp & 15;
#pragma unroll
                    for (int mt = 0; mt < 2; mt++)
                        af[sp & 3][mt] = *(const bf16x8*)(P + mt * 8192 + so * 32);
                }
                if (s + 1 < 16) {                  // B: 1 step ahead from LDS
#pragma unroll
                    for (int g2 = 0; g2 < 5; g2++)
                        bb[(s + 1) & 1][g2] =
                            *(const bf16x8*)(&Blds[g2 * 8192 + (s + 1) * 512 + lane * 8]);
                }
#pragma unroll
                for (int g2 = 0; g2 < 5; g2++)
#pragma unroll
                    for (int mt = 0; mt < 2; mt++)
                        acc[g2][mt] = __builtin_amdgcn_mfma_f32_16x16x32_bf16(
                            af[s & 3][mt], bb[s & 1][g2], acc[g2][mt], 0, 0, 0);
            }

#pragma unroll
            for (int mt = 0; mt < 2; mt++) {
#pragma unroll
                for (int v = 0; v < 4; v++) {
                    long grow = wrow + mt * 16 + q * 4 + v;
                    f32x4 xv = *(const f32x4*)(xg4 + (idv[mt][v] * 256 + gcol) * 4);
                    float fl = sigf(acc[0][mt][v] + xv.x);   // f_l,f_r share gate0
                    float fr = sigf(acc[1][mt][v] + xv.x);
                    float ig = sigf(acc[2][mt][v] + xv.y);
                    float og = sigf(acc[3][mt][v] + xv.z);
                    float ug = tanhfast(acc[4][mt][v] + xv.w);
                    float cv = ig * ug + fl * (float)clv[mt][v]
                                       + fr * (float)crv[mt][v];
                    float hv = og * tanhfast(cv);
                    h_out[grow * 256 + gcol] = (__bf16)hv;
                    c_out[grow * 256 + gcol] = (__bf16)cv;
                    if (rh_out) rh_out[grow * 256 + gcol] = hv;
                }
            }
        }
        Ap = Apn;
    }
}

#define LOADB5(dst)                                                            \
    do {                                                                       \
        dst[0] = *(const bf16x8*)bp0; dst[1] = *(const bf16x8*)bp1;            \
        dst[2] = *(const bf16x8*)bp2; dst[3] = *(const bf16x8*)bp3;            \
        dst[4] = *(const bf16x8*)bp4;                                          \
        bp0 += 512; bp1 += 512; bp2 += 512; bp3 += 512; bp4 += 512;            \
    } while (0)

// ===== tail: lev6..1 + scores. 64 blocks x 512 thr = 8 waves; each wave
// runs cts {w, w+8} sequentially (unroll-1 cp loop -> one cp live).
// __launch_bounds__(512,2) -> 256-reg budget: dbuf B pipelining fits.
// Stage lev7 output (128 rows h+c, swizzled). lev6 IN-PLACE (2 chunks,
// read/write phases); lev5..1 ping-pong [0,64)<->[64,96). K-loops: manual
// unroll-2, two named B buffers, 5 walking pointers.
__global__ __launch_bounds__(512, 2) void tail_kernel(
    const __bf16* __restrict__ Hin, const __bf16* __restrict__ Cin,
    const __bf16* __restrict__ BtP, const float* __restrict__ xg4,
    const int* __restrict__ ids, const float* __restrict__ Ws,
    const float* __restrict__ bs, float* __restrict__ out) {
    __shared__ __bf16 hbuf[128 * 256];   // 64 KB
    __shared__ __bf16 cbuf[128 * 256];   // 64 KB
    const int b    = blockIdx.x;
    const int tid  = threadIdx.x;
    const int wave = tid >> 6;           // 0..7
    const int lane = tid & 63;
    const int lr = lane & 15, q = lane >> 4;

    // ---- Stage lev-7 output (batch b: 128 rows) into rows [0,128), swizzled. --
#pragma unroll
    for (int i = 0; i < 8; i++) {
        int idx = tid + i * 512;             // 16B granule, 0..4095
        int row = idx >> 5;                  // 0..127
        int colb = (idx & 31) * 16;
        int dst = (row * 512 + colb) ^ (((row >> 1) & 7) << 4);
        *(i32x4*)((char*)hbuf + dst) =
            *(const i32x4*)(Hin + (long)(b * 128 + row) * 256 + (idx & 31) * 8);
        *(i32x4*)((char*)cbuf + dst) =
            *(const i32x4*)(Cin + (long)(b * 128 + row) * 256 + (idx & 31) * 8);
    }
    __syncthreads();

    // ---- lev6 IN-PLACE: n=64, 2 chunks of 32 parents. ----
#pragma unroll 1
    for (int ch = 0; ch < 2; ch++) {
        const int rbase = ch * 32;
        float hv6[2][2][4], cv6[2][2][4];    // [cp][mt][v]

        // READ PHASE: both ct passes (sequential; one cp's K-state live).
#pragma unroll 1
        for (int cp = 0; cp < 2; cp++) {
            const int ct   = wave + 8 * cp;
            const int gcol = ct * 16 + lr;

            int idv6[2][4];
            float clv6[2][4], crv6[2][4];
#pragma unroll
            for (int mt = 0; mt < 2; mt++)
#pragma unroll
                for (int v = 0; v < 4; v++) {
                    int j = rbase + mt * 16 + q * 4 + v;          // < 64
                    idv6[mt][v] = ids[b * 2046 + 62 + j];
                    int c0r = 2 * j, c1r = 2 * j + 1;
                    int a0 = (c0r * 512 + gcol * 2) ^ (((c0r >> 1) & 7) << 4);
                    int a1 = (c1r * 512 + gcol * 2) ^ (((c1r >> 1) & 7) << 4);
                    clv6[mt][v] = (float)*(const __bf16*)((const char*)cbuf + a0);
                    crv6[mt][v] = (float)*(const __bf16*)((const char*)cbuf + a1);
                }

            f32x4 acc[5][2];
#pragma unroll
            for (int g2 = 0; g2 < 5; g2++)
#pragma unroll
                for (int mt = 0; mt < 2; mt++)
                    acc[g2][mt] = (f32x4){0.f, 0.f, 0.f, 0.f};

            const __bf16* bp0 = BtP + (long)ct * 8192 + lane * 8;
            const __bf16* bp1 = bp0 + 131072;
            const __bf16* bp2 = bp0 + 262144;
            const __bf16* bp3 = bp0 + 393216;
            const __bf16* bp4 = bp0 + 524288;

            bf16x8 b0_[5], b1_[5];
            LOADB5(b0_);                      // s = 0

#pragma unroll 1
            for (int s2 = 0; s2 < 8; s2++) {
                const int s = s2 * 2;
                LOADB5(b1_);                  // prefetch s+1

                bf16x8 afv[2];
                {
                    int k0 = q * 8 + s * 32;
                    int crow = 2 * (rbase + lr) + (k0 >> 8);
                    int ab = (crow * 512 + (k0 & 255) * 2) ^ (((crow >> 1) & 7) << 4);
                    afv[0] = *(const bf16x8*)((const char*)hbuf + ab);
                    crow = 2 * (rbase + 16 + lr) + (k0 >> 8);
                    ab = (crow * 512 + (k0 & 255) * 2) ^ (((crow >> 1) & 7) << 4);
                    afv[1] = *(const bf16x8*)((const char*)hbuf + ab);
                }
#pragma unroll
                for (int g2 = 0; g2 < 5; g2++)
#pragma unroll
                    for (int mt = 0; mt < 2; mt++)
                        acc[g2][mt] = __builtin_amdgcn_mfma_f32_16x16x32_bf16(
                            afv[mt], b0_[g2], acc[g2][mt], 0, 0, 0);

                if (s2 < 7) LOADB5(b0_);      // prefetch s+2

                {
                    int k0 = q * 8 + (s + 1) * 32;
                    int crow = 2 * (rbase + lr) + (k0 >> 8);
                    int ab = (crow * 512 + (k0 & 255) * 2) ^ (((crow >> 1) & 7) << 4);
                    afv[0] = *(const bf16x8*)((const char*)hbuf + ab);
                    crow = 2 * (rbase + 16 + lr) + (k0 >> 8);
                    ab = (crow * 512 + (k0 & 255) * 2) ^ (((crow >> 1) & 7) << 4);
                    afv[1] = *(const bf16x8*)((const char*)hbuf + ab);
                }
#pragma unroll
                for (int g2 = 0; g2 < 5; g2++)
#pragma unroll
                    for (int mt = 0; mt < 2; mt++)
                        acc[g2][mt] = __builtin_amdgcn_mfma_f32_16x16x32_bf16(
                            afv[mt], b1_[g2], acc[g2][mt], 0, 0, 0);
            }

#pragma unroll
            for (int mt = 0; mt < 2; mt++)
#pragma unroll
                for (int v = 0; v < 4; v++) {
                    f32x4 xv = *(const f32x4*)(xg4 + (idv6[mt][v] * 256 + gcol) * 4);
                    float fl = sigf(acc[0][mt][v] + xv.x);
                    float fr = sigf(acc[1][mt][v] + xv.x);
                    float ig = sigf(acc[2][mt][v] + xv.y);
                    float og = sigf(acc[3][mt][v] + xv.z);
                    float ug = tanhfast(acc[4][mt][v] + xv.w);
                    float cv = ig * ug + fl * clv6[mt][v] + fr * crv6[mt][v];
                    cv6[cp][mt][v] = cv;
                    hv6[cp][mt][v] = og * tanhfast(cv);
                }
        }
        __syncthreads();    // all reads of this chunk complete

        // WRITE PHASE: rows rbase..rbase+31 (disjoint from other chunk's reads).
#pragma unroll
        for (int cp = 0; cp < 2; cp++) {
            const int gcol = (wave + 8 * cp) * 16 + lr;
#pragma unroll
            for (int mt = 0; mt < 2; mt++)
#pragma unroll
                for (int v = 0; v < 4; v++) {
                    int j = rbase + mt * 16 + q * 4 + v;
                    int dst = (j * 512 + gcol * 2) ^ (((j >> 1) & 7) << 4);
                    *(__bf16*)((char*)hbuf + dst) = (__bf16)hv6[cp][mt][v];
                    *(__bf16*)((char*)cbuf + dst) = (__bf16)cv6[cp][mt][v];
                }
        }
        __syncthreads();
    }

    // ---- lev5..1: ping-pong [0,64) <-> [64,96). ----
#pragma unroll 1
    for (int lev = 5; lev >= 1; lev--) {
        const int n   = 1 << lev;
        const int off = n - 2;
        const int p   = (5 - lev) & 1;
        const int rr  = p ? 64 : 0;          // read region start row
        const int wr  = p ? 0 : 64;          // write region start row
        const int mts = (n > 16) ? 2 : 1;

#pragma unroll 1
        for (int cp = 0; cp < 2; cp++) {
            const int ct   = wave + 8 * cp;
            const int gcol = ct * 16 + lr;

            int idv[2][4];
#pragma unroll
            for (int mt = 0; mt < 2; mt++)
#pragma unroll
                for (int v = 0; v < 4; v++) {
                    int j = mt * 16 + q * 4 + v;
                    idv[mt][v] = ids[b * 2046 + off + ((j < n) ? j : 0)];
                }

            f32x4 acc[5][2];
#pragma unroll
            for (int g2 = 0; g2 < 5; g2++)
#pragma unroll
                for (int mt = 0; mt < 2; mt++)
                    acc[g2][mt] = (f32x4){0.f, 0.f, 0.f, 0.f};

            const __bf16* bp0 = BtP + (long)ct * 8192 + lane * 8;
            const __bf16* bp1 = bp0 + 131072;
            const __bf16* bp2 = bp0 + 262144;
            const __bf16* bp3 = bp0 + 393216;
            const __bf16* bp4 = bp0 + 524288;

            bf16x8 b0_[5], b1_[5];
            LOADB5(b0_);                      // s = 0

#pragma unroll 1
            for (int s2 = 0; s2 < 8; s2++) {
                const int s = s2 * 2;
                LOADB5(b1_);                  // prefetch s+1

                bf16x8 afv[2];
                {
                    int k0 = q * 8 + s * 32;
                    int crow = rr + 2 * lr + (k0 >> 8);
                    int ab = (crow * 512 + (k0 & 255) * 2) ^ (((crow >> 1) & 7) << 4);
                    afv[0] = *(const bf16x8*)((const char*)hbuf + ab);
                    if (mts > 1) {
                        crow = rr + 2 * (16 + lr) + (k0 >> 8);
                        ab = (crow * 512 + (k0 & 255) * 2) ^ (((crow >> 1) & 7) << 4);
                        afv[1] = *(const bf16x8*)((const char*)hbuf + ab);
                    } else afv[1] = afv[0];
                }
#pragma unroll
                for (int g2 = 0; g2 < 5; g2++)
#pragma unroll
                    for (int mt = 0; mt < 2; mt++)
                        acc[g2][mt] = __builtin_amdgcn_mfma_f32_16x16x32_bf16(
                            afv[mt], b0_[g2], acc[g2][mt], 0, 0, 0);

                if (s2 < 7) LOADB5(b0_);      // prefetch s+2

                {
                    int k0 = q * 8 + (s + 1) * 32;
                    int crow = rr + 2 * lr + (k0 >> 8);
                    int ab = (crow * 512 + (k0 & 255) * 2) ^ (((crow >> 1) & 7) << 4);
                    afv[0] = *(const bf16x8*)((const char*)hbuf + ab);
                    if (mts > 1) {
                        crow = rr + 2 * (16 + lr) + (k0 >> 8);
                        ab = (crow * 512 + (k0 & 255) * 2) ^ (((crow >> 1) & 7) << 4);
                        afv[1] = *(const bf16x8*)((const char*)hbuf + ab);
                    } else afv[1] = afv[0];
                }
#pragma unroll
                for (int g2 = 0; g2 < 5; g2++)
#pragma unroll
                    for (int mt = 0; mt < 2; mt++)
                        acc[g2][mt] = __builtin_amdgcn_mfma_f32_16x16x32_bf16(
                            afv[mt], b1_[g2], acc[g2][mt], 0, 0, 0);
            }

            // Epilogue: write region disjoint from read region -> immediate.
#pragma unroll
            for (int mt = 0; mt < 2; mt++) {
#pragma unroll
                for (int v = 0; v < 4; v++) {
                    int j = mt * 16 + q * 4 + v;
                    if (mt < mts && j < n) {
                        int c0r = rr + 2 * j, c1r = rr + 2 * j + 1;
                        int a0 = (c0r * 512 + gcol * 2) ^ (((c0r >> 1) & 7) << 4);
                        int a1 = (c1r * 512 + gcol * 2) ^ (((c1r >> 1) & 7) << 4);
                        float cl = (float)*(const __bf16*)((const char*)cbuf + a0);
                        float cr = (float)*(const __bf16*)((const char*)cbuf + a1);
                        f32x4 xv = *(const f32x4*)(xg4 + (idv[mt][v] * 256 + gcol) * 4);
                        float fl = sigf(acc[0][mt][v] + xv.x);
                        float fr = sigf(acc[1][mt][v] + xv.x);
                        float ig = sigf(acc[2][mt][v] + xv.y);
                        float og = sigf(acc[3][mt][v] + xv.z);
                        float ug = tanhfast(acc[4][mt][v] + xv.w);
                        float cv = ig * ug + fl * cl + fr * cr;
                        float hv = og * tanhfast(cv);
                        int drow = wr + j;
                        int dst = (drow * 512 + gcol * 2) ^ (((drow >> 1) & 7) << 4);
                        *(__bf16*)((char*)hbuf + dst) = (__bf16)hv;
                        if (lev > 1) *(__bf16*)((char*)cbuf + dst) = (__bf16)cv;
                        if (lev == 1) out[192 + b * 512 + j * 256 + gcol] = hv;
                    }
                }
            }
        }
        __syncthreads();
    }

    // ---- scores: lev1 h sits in rows 64,65 (swizzle identity there). ----
    if (tid < 192) {
        int t = tid >> 6, ln = tid & 63;
        float s = 0.f;
        for (int i = ln; i < 512; i += 64) {
            int row = 64 + (i >> 8);
            float hv = (float)hbuf[row * 256 + (i & 255)];
            s += hv * Ws[i * 3 + t];
        }
        for (int o = 32; o > 0; o >>= 1) s += __shfl_down(s, o);
        if (ln == 0) out[b * 3 + t] = s + bs[t];
    }
}

extern "C" void kernel_launch(void* const* d_in, const int* in_sizes, int n_in,
                              void* d_out, int out_size, void* d_ws, size_t ws_size,
                              hipStream_t stream) {
    const int*   ids = (const int*)  d_in[0];
    const float* emb = (const float*)d_in[1];
    const float* W   = (const float*)d_in[2];
    const float* bW  = (const float*)d_in[3];
    const float* U   = (const float*)d_in[4];
    const float* Ws  = (const float*)d_in[5];
    const float* bs  = (const float*)d_in[6];
    float* out = (float*)d_out;   // [0:192) scores, [192:) root_hidden (64x512)

    char* ws = (char*)d_ws;
    float*  xg4 = (float*)ws;                   //   262144 B : xg4[64][256][4]
    __bf16* BtP = (__bf16*)(ws + 262144);       //  1310720 B : packed B fragments
    __bf16* h0  = (__bf16*)(ws + 1572864);      // 33554432 B : h ping (leaf-sized)
    __bf16* c0  = (__bf16*)(ws + 35127296);     // 33554432 B
    __bf16* h1  = (__bf16*)(ws + 68681728);     // 16777216 B : h pong
    __bf16* c1  = (__bf16*)(ws + 85458944);     // 16777216 B   (total 102236160 B)

    prep_kernel<<<dim3(576), dim3(256), 0, stream>>>(emb, W, bW, U, xg4, BtP);
    leaf_kernel<<<dim3(2048), dim3(256), 0, stream>>>(ids, xg4, h0, c0);

    __bf16* hb[2] = {h0, h1};
    __bf16* cb[2] = {c0, c1};
    int cur = 0;
    for (int lev = 9; lev >= 7; lev--) {
        int M = 64 << lev;                      // B * 2^lev rows
        int RG = M >> 9;
        int NB = (RG < 16) ? RG : 16;
        level_kernel<<<dim3(16 * NB), dim3(1024), 0, stream>>>(
            hb[cur], cb[cur], BtP, xg4, ids, hb[1 - cur], cb[1 - cur], nullptr,
            lev, M, RG, NB, (NB == 16) ? 1 : 0);
        cur = 1 - cur;
    }
    // after lev7: cur==1 -> h1/c1 hold lev-7 output (8192 rows = 64 x 128)
    tail_kernel<<<dim3(64), dim3(512), 0, stream>>>(
        hb[cur], cb[cur], BtP, xg4, ids, Ws, bs, out);
}

// Round 17
// 368.428 us; speedup vs baseline: 1.1524x; 1.0235x over previous
//
#include <hip/hip_runtime.h>
#include <hip/hip_bf16.h>
#include <stdint.h>
#include <math.h>

// TreeLSTM on MI355X — v24 = v20 byte-exact (verified 369.7us, session best).
// Final state after the tail campaign (v21/v22/v23): folding lev6 into the
// tail is net-negative (~+6us) — the 64-block tail's per-level latency
// (~15us) is invariant under unroll-1 / dbuf-pipelining / 8-vs-16-wave
// geometry (v21 vs v23: 15.0 vs 15.8 us/pass), so fewer dispatches don't
// pay. Cross-block sync is dead on MI355X (grid.sync ~115us, spin-bar
// ~24us). Spill laws learned: (1) global-B streaming in a fully-unrolled
// MFMA loop -> ~80 hoisted addresses -> scratch; fix = rolled loop +
// walking pointers. (2) 1024-thr blocks cap at 128 regs/wave; dbuf needs
// ~150. (3) s_setprio inside an unrolled K-loop -> live-range blowup.
// (4) dense reductions via global atomics -> 200us serialization.

typedef __bf16 bf16x8 __attribute__((ext_vector_type(8)));
typedef float  f32x4  __attribute__((ext_vector_type(4)));
typedef int    i32x4  __attribute__((ext_vector_type(4)));

__device__ __forceinline__ float sigf(float x) { return 1.f / (1.f + __expf(-x)); }
__device__ __forceinline__ float tanhfast(float x) {
    return 1.f - 2.f / (__expf(2.f * x) + 1.f);   // stable at |x| large
}

// blocks 0..255: xg4; blocks 256..575: BtP pack.
__global__ void prep_kernel(const float* __restrict__ emb, const float* __restrict__ W,
                            const float* __restrict__ bW, const float* __restrict__ U,
                            float* __restrict__ xg4, __bf16* __restrict__ BtP) {
    if (blockIdx.x < 256) {
        int g = blockIdx.x >> 6, v = blockIdx.x & 63, k = threadIdx.x;
        __shared__ float e[256];
        e[k] = emb[v * 256 + k];
        __syncthreads();
        float s = bW[g * 256 + k];
        const float* Wg = W + g * 65536 + k;
#pragma unroll 4
        for (int i = 0; i < 256; i++) s += e[i] * Wg[i * 256];
        xg4[(v * 256 + k) * 4 + g] = s;
    } else {
        int t = (blockIdx.x - 256) * 256 + threadIdx.x;   // < 81920
        int g    = t >> 14;
        int r    = t & 16383;
        int ct   = r >> 10;
        int ks   = (r >> 6) & 15;
        int lane = t & 63;
        int lr = lane & 15, q = lane >> 4;
        int col = ct * 16 + lr;
        int kbase = ks * 32 + q * 8;
        bf16x8 v8;
#pragma unroll
        for (int e2 = 0; e2 < 8; e2++) {
            int k = kbase + e2;
            int s = k >> 8, kk = k & 255;
            v8[e2] = (__bf16)U[((g * 2 + s) * 256 + kk) * 256 + col];
        }
        *(bf16x8*)(BtP + (long)t * 8) = v8;
    }
}

__global__ void leaf_kernel(const int* __restrict__ ids, const float* __restrict__ xg4,
                            __bf16* __restrict__ h, __bf16* __restrict__ c) {
    int col = threadIdx.x;                 // 0..255
    int r0 = blockIdx.x * 32;              // 2048 blocks x 32 rows
    for (int r = r0; r < r0 + 32; r++) {
        int b = r >> 10, j = r & 1023;
        int id = ids[b * 2046 + 1022 + j];
        f32x4 xv = *(const f32x4*)(xg4 + (id * 256 + col) * 4);
        float ig = sigf(xv.y);
        float og = sigf(xv.z);
        float ug = tanhfast(xv.w);
        float cv = ig * ug;
        float hv = og * tanhfast(cv);
        h[r * 256 + col] = (__bf16)hv;
        c[r * 256 + col] = (__bf16)cv;
    }
}

// ===== big levels (9..6): v12b measured kernel, byte-exact =====
__global__ __launch_bounds__(1024, 4) void level_kernel(
    const __bf16* __restrict__ A, const __bf16* __restrict__ Cprev,
    const __bf16* __restrict__ BtP, const float* __restrict__ xg4,
    const int* __restrict__ ids, __bf16* __restrict__ h_out,
    __bf16* __restrict__ c_out, float* __restrict__ rh_out,
    int lev, int M, int RG, int NB, int NB16) {
    __shared__ __bf16 Blds[5 * 16 * 512];     // 80 KB
    const int gid = blockIdx.x;
    int rgslot, ct;
    if (NB16) { rgslot = gid & 15; ct = gid >> 4; }   // XCD-affine: gid%8==rg%8
    else      { rgslot = gid % NB; ct = gid / NB; }
    const int tid  = threadIdx.x;
    const int wave = tid >> 6;
    const int lane = tid & 63;
    const int lr = lane & 15, q = lane >> 4;
    const int gcol = ct * 16 + lr;
    const int n = 1 << lev;

#pragma unroll
    for (int i = 0; i < 5; i++) {
        int cc = tid + i * 1024;
        int g = cc >> 10;
        int r = cc & 1023;
        *(i32x4*)(&Blds[g * 8192 + r * 8]) =
            *(const i32x4*)(BtP + (long)(g * 16 + ct) * 8192 + r * 8);
    }
    __syncthreads();

    int rg0 = rgslot;
    long wrow = (long)rg0 * 512 + wave * 32;
    const __bf16* Ap = A + (wrow + lr) * 512 + q * 8;   // + mt*8192 + s*32
    bf16x8 af[4][2];
    if (wrow < M) {
#pragma unroll
        for (int mt = 0; mt < 2; mt++) {
            af[0][mt] = *(const bf16x8*)(Ap + mt * 8192);
            af[1][mt] = *(const bf16x8*)(Ap + mt * 8192 + 32);
        }
    }

    for (int rg = rg0; rg < RG; rg += NB) {
        wrow = (long)rg * 512 + wave * 32;
        const bool active = (wrow < M);

        int rgn = rg + NB;
        long wrown = (rgn < RG) ? ((long)rgn * 512 + wave * 32) : wrow;
        const __bf16* Apn = A + (wrown + lr) * 512 + q * 8;

        int idv[2][4];
        __bf16 clv[2][4], crv[2][4];
        if (active) {
#pragma unroll
            for (int mt = 0; mt < 2; mt++)
#pragma unroll
                for (int v = 0; v < 4; v++) {
                    long grow = wrow + mt * 16 + q * 4 + v;
                    int b = (int)(grow >> lev);
                    int j = (int)(grow & (n - 1));
                    idv[mt][v] = ids[b * 2046 + (n - 2) + j];
                    clv[mt][v] = Cprev[grow * 512 + gcol];
                    crv[mt][v] = Cprev[grow * 512 + 256 + gcol];
                }
        }

        if (active) {
            f32x4 acc[5][2];
#pragma unroll
            for (int g2 = 0; g2 < 5; g2++)
#pragma unroll
                for (int mt = 0; mt < 2; mt++)
                    acc[g2][mt] = (f32x4){0.f, 0.f, 0.f, 0.f};

            bf16x8 bb[2][5];
#pragma unroll
            for (int g2 = 0; g2 < 5; g2++)
                bb[0][g2] = *(const bf16x8*)(&Blds[g2 * 8192 + lane * 8]);

#pragma unroll
            for (int s = 0; s < 16; s++) {
                {   // A: 2 ahead; wraps into NEXT rg's steps 0,1 at s=14,15.
                    int sp = s + 2;
                    const __bf16* P = (sp < 16) ? Ap : Apn;
                    int so = sp & 15;
#pragma unroll
                    for (int mt = 0; mt < 2; mt++)
                        af[sp & 3][mt] = *(const bf16x8*)(P + mt * 8192 + so * 32);
                }
                if (s + 1 < 16) {                  // B: 1 step ahead from LDS
#pragma unroll
                    for (int g2 = 0; g2 < 5; g2++)
                        bb[(s + 1) & 1][g2] =
                            *(const bf16x8*)(&Blds[g2 * 8192 + (s + 1) * 512 + lane * 8]);
                }
#pragma unroll
                for (int g2 = 0; g2 < 5; g2++)
#pragma unroll
                    for (int mt = 0; mt < 2; mt++)
                        acc[g2][mt] = __builtin_amdgcn_mfma_f32_16x16x32_bf16(
                            af[s & 3][mt], bb[s & 1][g2], acc[g2][mt], 0, 0, 0);
            }

#pragma unroll
            for (int mt = 0; mt < 2; mt++) {
#pragma unroll
                for (int v = 0; v < 4; v++) {
                    long grow = wrow + mt * 16 + q * 4 + v;
                    f32x4 xv = *(const f32x4*)(xg4 + (idv[mt][v] * 256 + gcol) * 4);
                    float fl = sigf(acc[0][mt][v] + xv.x);   // f_l,f_r share gate0
                    float fr = sigf(acc[1][mt][v] + xv.x);
                    float ig = sigf(acc[2][mt][v] + xv.y);
                    float og = sigf(acc[3][mt][v] + xv.z);
                    float ug = tanhfast(acc[4][mt][v] + xv.w);
                    float cv = ig * ug + fl * (float)clv[mt][v]
                                       + fr * (float)crv[mt][v];
                    float hv = og * tanhfast(cv);
                    h_out[grow * 256 + gcol] = (__bf16)hv;
                    c_out[grow * 256 + gcol] = (__bf16)cv;
                    if (rh_out) rh_out[grow * 256 + gcol] = hv;
                }
            }
        }
        Ap = Apn;
    }
}

// ===== tail: lev5..1 + scores. 64 blocks (one per batch), 1024 thr = 16
// waves (wave = ct). h/c in LDS ping-pong with XOR swizzle. K-loop ROLLED,
// B via 5 incrementally-advanced pointers — the spill fix. MFMA runs both
// m-tiles unguarded (extra work harmless at n<=16; loads/stores guarded).
__global__ __launch_bounds__(1024, 4) void tail_kernel(
    const __bf16* __restrict__ Hin, const __bf16* __restrict__ Cin,
    const __bf16* __restrict__ BtP, const float* __restrict__ xg4,
    const int* __restrict__ ids, const float* __restrict__ Ws,
    const float* __restrict__ bs, float* __restrict__ out) {
    __shared__ __bf16 hbuf[96 * 256];    // 48 KB
    __shared__ __bf16 cbuf[96 * 256];    // 48 KB
    const int b    = blockIdx.x;
    const int tid  = threadIdx.x;
    const int wave = tid >> 6;           // = ct
    const int lane = tid & 63;
    const int lr = lane & 15, q = lane >> 4;
    const int ct   = wave;
    const int gcol = ct * 16 + lr;

    // ---- Stage lev-6 output (batch b: 64 rows) into R0, swizzled. ----
#pragma unroll
    for (int i = 0; i < 2; i++) {
        int idx = tid + i * 1024;            // 16B granule, 0..2047
        int row = idx >> 5;                  // 0..63
        int colb = (idx & 31) * 16;
        int dst = (row * 512 + colb) ^ (((row >> 1) & 7) << 4);
        *(i32x4*)((char*)hbuf + dst) =
            *(const i32x4*)(Hin + (long)(b * 64 + row) * 256 + (idx & 31) * 8);
        *(i32x4*)((char*)cbuf + dst) =
            *(const i32x4*)(Cin + (long)(b * 64 + row) * 256 + (idx & 31) * 8);
    }
    __syncthreads();

    const __bf16* Bbase = BtP + (long)ct * 8192 + lane * 8;  // + g2*131072 + s*512

#pragma unroll 1
    for (int lev = 5; lev >= 1; lev--) {
        const int n   = 1 << lev;
        const int off = n - 2;
        const int p   = (5 - lev) & 1;
        const int rr  = p ? 64 : 0;          // read region start row
        const int wr  = p ? 0 : 64;          // write region start row
        const int mts = (n > 16) ? 2 : 1;

        // Preload ids (hide gather latency under the K-loop).
        int idv[2][4];
#pragma unroll
        for (int mt = 0; mt < 2; mt++)
#pragma unroll
            for (int v = 0; v < 4; v++) {
                int j = mt * 16 + q * 4 + v;
                idv[mt][v] = ids[b * 2046 + off + ((j < n) ? j : 0)];
            }

        f32x4 acc[5][2];
#pragma unroll
        for (int g2 = 0; g2 < 5; g2++)
#pragma unroll
            for (int mt = 0; mt < 2; mt++)
                acc[g2][mt] = (f32x4){0.f, 0.f, 0.f, 0.f};

        // 5 walking B pointers (incremental addressing — no hoisted table).
        const __bf16* bp0 = Bbase;
        const __bf16* bp1 = Bbase + 131072;
        const __bf16* bp2 = Bbase + 262144;
        const __bf16* bp3 = Bbase + 393216;
        const __bf16* bp4 = Bbase + 524288;

#pragma unroll 1
        for (int s = 0; s < 16; s++) {
            bf16x8 bbv[5];
            bbv[0] = *(const bf16x8*)bp0;
            bbv[1] = *(const bf16x8*)bp1;
            bbv[2] = *(const bf16x8*)bp2;
            bbv[3] = *(const bf16x8*)bp3;
            bbv[4] = *(const bf16x8*)bp4;
            bp0 += 512; bp1 += 512; bp2 += 512; bp3 += 512; bp4 += 512;

            bf16x8 afv[2];
            {
                int k0 = q * 8 + s * 32;
                int crow = rr + 2 * lr + (k0 >> 8);
                int ab = (crow * 512 + (k0 & 255) * 2) ^ (((crow >> 1) & 7) << 4);
                afv[0] = *(const bf16x8*)((const char*)hbuf + ab);
            }
            if (mts > 1) {
                int k0 = q * 8 + s * 32;
                int crow = rr + 2 * (16 + lr) + (k0 >> 8);
                int ab = (crow * 512 + (k0 & 255) * 2) ^ (((crow >> 1) & 7) << 4);
                afv[1] = *(const bf16x8*)((const char*)hbuf + ab);
            } else {
                afv[1] = afv[0];
            }

#pragma unroll
            for (int g2 = 0; g2 < 5; g2++)
#pragma unroll
                for (int mt = 0; mt < 2; mt++)
                    acc[g2][mt] = __builtin_amdgcn_mfma_f32_16x16x32_bf16(
                        afv[mt], bbv[g2], acc[g2][mt], 0, 0, 0);
        }

        // ---- Epilogue: c from LDS read-region; write h/c to write-region. ----
#pragma unroll
        for (int mt = 0; mt < 2; mt++) {
#pragma unroll
            for (int v = 0; v < 4; v++) {
                int j = mt * 16 + q * 4 + v;
                if (mt < mts && j < n) {
                    int c0r = rr + 2 * j, c1r = rr + 2 * j + 1;
                    int a0 = (c0r * 512 + gcol * 2) ^ (((c0r >> 1) & 7) << 4);
                    int a1 = (c1r * 512 + gcol * 2) ^ (((c1r >> 1) & 7) << 4);
                    float cl = (float)*(const __bf16*)((const char*)cbuf + a0);
                    float cr = (float)*(const __bf16*)((const char*)cbuf + a1);
                    f32x4 xv = *(const f32x4*)(xg4 + (idv[mt][v] * 256 + gcol) * 4);
                    float fl = sigf(acc[0][mt][v] + xv.x);
                    float fr = sigf(acc[1][mt][v] + xv.x);
                    float ig = sigf(acc[2][mt][v] + xv.y);
                    float og = sigf(acc[3][mt][v] + xv.z);
                    float ug = tanhfast(acc[4][mt][v] + xv.w);
                    float cv = ig * ug + fl * cl + fr * cr;
                    float hv = og * tanhfast(cv);
                    int drow = wr + j;
                    int dst = (drow * 512 + gcol * 2) ^ (((drow >> 1) & 7) << 4);
                    *(__bf16*)((char*)hbuf + dst) = (__bf16)hv;
                    if (lev > 1) *(__bf16*)((char*)cbuf + dst) = (__bf16)cv;
                    if (lev == 1) out[192 + b * 512 + j * 256 + gcol] = hv;
                }
            }
        }
        __syncthreads();
    }

    // ---- scores: lev1 h sits in rows 64,65 (swizzle identity there). ----
    if (tid < 192) {
        int t = tid >> 6, ln = tid & 63;
        float s = 0.f;
        for (int i = ln; i < 512; i += 64) {
            int row = 64 + (i >> 8);
            float hv = (float)hbuf[row * 256 + (i & 255)];
            s += hv * Ws[i * 3 + t];
        }
        for (int o = 32; o > 0; o >>= 1) s += __shfl_down(s, o);
        if (ln == 0) out[b * 3 + t] = s + bs[t];
    }
}

extern "C" void kernel_launch(void* const* d_in, const int* in_sizes, int n_in,
                              void* d_out, int out_size, void* d_ws, size_t ws_size,
                              hipStream_t stream) {
    const int*   ids = (const int*)  d_in[0];
    const float* emb = (const float*)d_in[1];
    const float* W   = (const float*)d_in[2];
    const float* bW  = (const float*)d_in[3];
    const float* U   = (const float*)d_in[4];
    const float* Ws  = (const float*)d_in[5];
    const float* bs  = (const float*)d_in[6];
    float* out = (float*)d_out;   // [0:192) scores, [192:) root_hidden (64x512)

    char* ws = (char*)d_ws;
    float*  xg4 = (float*)ws;                   //   262144 B : xg4[64][256][4]
    __bf16* BtP = (__bf16*)(ws + 262144);       //  1310720 B : packed B fragments
    __bf16* h0  = (__bf16*)(ws + 1572864);      // 33554432 B : h ping (leaf-sized)
    __bf16* c0  = (__bf16*)(ws + 35127296);     // 33554432 B
    __bf16* h1  = (__bf16*)(ws + 68681728);     // 16777216 B : h pong
    __bf16* c1  = (__bf16*)(ws + 85458944);     // 16777216 B   (total 102236160 B)

    prep_kernel<<<dim3(576), dim3(256), 0, stream>>>(emb, W, bW, U, xg4, BtP);
    leaf_kernel<<<dim3(2048), dim3(256), 0, stream>>>(ids, xg4, h0, c0);

    __bf16* hb[2] = {h0, h1};
    __bf16* cb[2] = {c0, c1};
    int cur = 0;
    for (int lev = 9; lev >= 6; lev--) {
        int M = 64 << lev;                      // B * 2^lev rows
        int RG = M >> 9;
        int NB = (RG < 16) ? RG : 16;
        level_kernel<<<dim3(16 * NB), dim3(1024), 0, stream>>>(
            hb[cur], cb[cur], BtP, xg4, ids, hb[1 - cur], cb[1 - cur], nullptr,
            lev, M, RG, NB, (NB == 16) ? 1 : 0);
        cur = 1 - cur;
    }
    // after lev6: cur==0 -> h0/c0 hold lev-6 output (4096 rows = 64 x 64)
    tail_kernel<<<dim3(64), dim3(1024), 0, stream>>>(
        hb[cur], cb[cur], BtP, xg4, ids, Ws, bs, out);
}